// Round 1
// baseline (660.971 us; speedup 1.0000x reference)
//
#include <hip/hip_runtime.h>

#define NDIM 128     // OUT_DIM
#define KDIM 256     // IN_DIM
#define GR   16      // node rows per GEMM block
#define SCAN_T 1024

// ---------- Wc = Wg @ Wp, stored transposed: WcT[i*128+o] = sum_k Wg[o][k]*Wp[k][i]
__global__ void k_combine_w(const float* __restrict__ Wp, const float* __restrict__ Wg,
                            float* __restrict__ WcT) {
    int o = blockIdx.x;      // 0..127
    int i = threadIdx.x;     // 0..255
    float acc = 0.f;
#pragma unroll 4
    for (int k = 0; k < 128; ++k) acc = fmaf(Wg[o * 128 + k], Wp[k * 256 + i], acc);
    WcT[i * NDIM + o] = acc;
}

__global__ void k_zero(int* __restrict__ p, int n) {
    int i = blockIdx.x * blockDim.x + threadIdx.x;
    if (i < n) p[i] = 0;
}

// ---------- histogram of target (col) indices
__global__ void k_hist(const int* __restrict__ col, int* __restrict__ cnt, int E) {
    int e = blockIdx.x * blockDim.x + threadIdx.x;
    if (e < E) atomicAdd(&cnt[col[e]], 1);
}

// ---------- exclusive scan, 3-kernel version (N=100000 -> 98 tiles of 1024)
__global__ __launch_bounds__(SCAN_T) void k_scan_blocks(const int* __restrict__ cnt, int n,
                                                        int* __restrict__ excl,
                                                        int* __restrict__ blockSums) {
    __shared__ int s[SCAN_T];
    int t = threadIdx.x;
    int i = blockIdx.x * SCAN_T + t;
    int v = (i < n) ? cnt[i] : 0;
    s[t] = v;
    __syncthreads();
    for (int d = 1; d < SCAN_T; d <<= 1) {
        int y = (t >= d) ? s[t - d] : 0;
        __syncthreads();
        s[t] += y;
        __syncthreads();
    }
    if (i < n) excl[i] = s[t] - v;
    if (t == SCAN_T - 1) blockSums[blockIdx.x] = s[t];
}

__global__ __launch_bounds__(SCAN_T) void k_scan_sums(int* __restrict__ blockSums, int nb) {
    __shared__ int s[SCAN_T];
    int t = threadIdx.x;
    int v = (t < nb) ? blockSums[t] : 0;
    s[t] = v;
    __syncthreads();
    for (int d = 1; d < SCAN_T; d <<= 1) {
        int y = (t >= d) ? s[t - d] : 0;
        __syncthreads();
        s[t] += y;
        __syncthreads();
    }
    if (t < nb) blockSums[t] = s[t] - v;   // exclusive
}

__global__ __launch_bounds__(SCAN_T) void k_finalize(int* __restrict__ rowStart,
                                                     const int* __restrict__ blockSums,
                                                     int n, int E, int* __restrict__ cursor) {
    int t = threadIdx.x;
    int i = blockIdx.x * SCAN_T + t;
    if (i < n) {
        int v = rowStart[i] + blockSums[blockIdx.x];
        rowStart[i] = v;
        cursor[i]   = v;
    }
    if (i == 0) rowStart[n] = E;
}

// ---------- bucket sources by target
__global__ void k_fill(const int* __restrict__ ei, int E, int* __restrict__ cursor,
                       int* __restrict__ sortedRow) {
    int e = blockIdx.x * blockDim.x + threadIdx.x;
    if (e < E) {
        int r = ei[e];          // source
        int c = ei[E + e];      // target
        int p = atomicAdd(&cursor[c], 1);
        sortedRow[p] = r;
    }
}

// ---------- g = dinv * (x @ WcT); 16 rows x 128 outs per block, f32 VALU
__global__ __launch_bounds__(128) void k_gemm(const float* __restrict__ x,
                                              const float* __restrict__ WcT,
                                              const int* __restrict__ cnt,
                                              float* __restrict__ g, int n) {
    __shared__ float xs[GR * KDIM];
    int o = threadIdx.x;                       // output dim 0..127
    long n0 = (long)blockIdx.x * GR;
    const float4* xv = (const float4*)(x + n0 * KDIM);
    float4* sv = (float4*)xs;
#pragma unroll
    for (int idx = o; idx < GR * KDIM / 4; idx += 128) sv[idx] = xv[idx];
    __syncthreads();

    float acc[GR];
#pragma unroll
    for (int r = 0; r < GR; ++r) acc[r] = 0.f;

    for (int k4 = 0; k4 < KDIM / 4; ++k4) {
        float w0 = WcT[(k4 * 4 + 0) * NDIM + o];
        float w1 = WcT[(k4 * 4 + 1) * NDIM + o];
        float w2 = WcT[(k4 * 4 + 2) * NDIM + o];
        float w3 = WcT[(k4 * 4 + 3) * NDIM + o];
#pragma unroll
        for (int r = 0; r < GR; ++r) {
            float4 xr = *(const float4*)&xs[r * KDIM + k4 * 4];
            acc[r] = fmaf(xr.x, w0, acc[r]);
            acc[r] = fmaf(xr.y, w1, acc[r]);
            acc[r] = fmaf(xr.z, w2, acc[r]);
            acc[r] = fmaf(xr.w, w3, acc[r]);
        }
    }
#pragma unroll
    for (int r = 0; r < GR; ++r) {
        long node = n0 + r;
        float di = rsqrtf((float)(cnt[node] + 1));   // deg = cnt + self-loop
        g[node * NDIM + o] = acc[r] * di;
    }
}

// ---------- gather + scale + bias + row L2-normalize (one block per node)
__global__ __launch_bounds__(128) void k_gather(const float* __restrict__ g,
                                                const int* __restrict__ rowStart,
                                                const int* __restrict__ sortedRow,
                                                const int* __restrict__ cnt,
                                                const float* __restrict__ bg,
                                                float* __restrict__ out) {
    int i = blockIdx.x;
    int o = threadIdx.x;
    long base = (long)i * NDIM;
    int s = rowStart[i];
    int e = rowStart[i + 1];
    float acc = g[base + o];                 // self-loop message = g[i]
    for (int p = s; p < e; ++p) {
        int r = sortedRow[p];
        acc += g[(long)r * NDIM + o];
    }
    float di = rsqrtf((float)(cnt[i] + 1));
    float v = fmaf(di, acc, bg[o]);

    float sq = v * v;
#pragma unroll
    for (int d = 32; d > 0; d >>= 1) sq += __shfl_down(sq, d);
    __shared__ float ssum[2];
    if ((o & 63) == 0) ssum[o >> 6] = sq;
    __syncthreads();
    float nrm = sqrtf(ssum[0] + ssum[1]);
    float scale = 1.0f / fmaxf(nrm, 1e-12f);
    out[base + o] = v * scale;
}

extern "C" void kernel_launch(void* const* d_in, const int* in_sizes, int n_in,
                              void* d_out, int out_size, void* d_ws, size_t ws_size,
                              hipStream_t stream) {
    const float* x  = (const float*)d_in[0];
    const int*   ei = (const int*)  d_in[1];
    const float* Wp = (const float*)d_in[2];
    const float* Wg = (const float*)d_in[3];
    const float* bg = (const float*)d_in[4];
    float* out = (float*)d_out;

    const int N = in_sizes[0] / KDIM;   // 100000
    const int E = in_sizes[1] / 2;      // 1600000

    // carve workspace (256B aligned)
    char* p = (char*)d_ws;
    auto carve = [&](size_t bytes) { void* r = (void*)p; p += (bytes + 255) & ~(size_t)255; return r; };
    float* g         = (float*)carve((size_t)N * NDIM * 4);   // 51.2 MB
    int*   sortedRow = (int*)  carve((size_t)E * 4);          // 6.4 MB
    float* WcT       = (float*)carve((size_t)KDIM * NDIM * 4);
    int*   cnt       = (int*)  carve((size_t)N * 4);
    int*   rowStart  = (int*)  carve((size_t)(N + 1) * 4);
    int*   cursor    = (int*)  carve((size_t)N * 4);
    int*   blockSums = (int*)  carve((size_t)SCAN_T * 4);

    int nb = (N + SCAN_T - 1) / SCAN_T;   // 98 (fits in one SCAN_T-wide scan)

    hipLaunchKernelGGL(k_combine_w, dim3(NDIM), dim3(KDIM), 0, stream, Wp, Wg, WcT);
    hipLaunchKernelGGL(k_zero, dim3((N + 255) / 256), dim3(256), 0, stream, cnt, N);
    hipLaunchKernelGGL(k_hist, dim3((E + 255) / 256), dim3(256), 0, stream, ei + E, cnt, E);
    hipLaunchKernelGGL(k_scan_blocks, dim3(nb), dim3(SCAN_T), 0, stream, cnt, N, rowStart, blockSums);
    hipLaunchKernelGGL(k_scan_sums, dim3(1), dim3(SCAN_T), 0, stream, blockSums, nb);
    hipLaunchKernelGGL(k_finalize, dim3(nb), dim3(SCAN_T), 0, stream, rowStart, blockSums, N, E, cursor);
    hipLaunchKernelGGL(k_fill, dim3((E + 255) / 256), dim3(256), 0, stream, ei, E, cursor, sortedRow);
    hipLaunchKernelGGL(k_gemm, dim3(N / GR), dim3(NDIM), 0, stream, x, WcT, cnt, g, N);
    hipLaunchKernelGGL(k_gather, dim3(N), dim3(NDIM), 0, stream, g, rowStart, sortedRow, cnt, bg, out);
}

// Round 3
// 569.162 us; speedup vs baseline: 1.1613x; 1.1613x over previous
//
#include <hip/hip_runtime.h>
#include <hip/hip_fp16.h>

#define NDIM 128     // OUT_DIM
#define KDIM 256     // IN_DIM
#define GR   16      // node rows per GEMM block
#define SCAN_T 1024

// ---------- Wc = Wg @ Wp, stored transposed: WcT[i*128+o] = sum_k Wg[o][k]*Wp[k][i]
__global__ void k_combine_w(const float* __restrict__ Wp, const float* __restrict__ Wg,
                            float* __restrict__ WcT) {
    int o = blockIdx.x;      // 0..127
    int i = threadIdx.x;     // 0..255
    float acc = 0.f;
#pragma unroll 4
    for (int k = 0; k < 128; ++k) acc = fmaf(Wg[o * 128 + k], Wp[k * 256 + i], acc);
    WcT[i * NDIM + o] = acc;
}

__global__ void k_zero(int* __restrict__ p, int n) {
    int i = blockIdx.x * blockDim.x + threadIdx.x;
    if (i < n) p[i] = 0;
}

// ---------- histogram of target (col) indices
__global__ void k_hist(const int* __restrict__ col, int* __restrict__ cnt, int E) {
    int e = blockIdx.x * blockDim.x + threadIdx.x;
    if (e < E) atomicAdd(&cnt[col[e]], 1);
}

// ---------- exclusive scan, 3-kernel version (N=100000 -> 98 tiles of 1024)
__global__ __launch_bounds__(SCAN_T) void k_scan_blocks(const int* __restrict__ cnt, int n,
                                                        int* __restrict__ excl,
                                                        int* __restrict__ blockSums) {
    __shared__ int s[SCAN_T];
    int t = threadIdx.x;
    int i = blockIdx.x * SCAN_T + t;
    int v = (i < n) ? cnt[i] : 0;
    s[t] = v;
    __syncthreads();
    for (int d = 1; d < SCAN_T; d <<= 1) {
        int y = (t >= d) ? s[t - d] : 0;
        __syncthreads();
        s[t] += y;
        __syncthreads();
    }
    if (i < n) excl[i] = s[t] - v;
    if (t == SCAN_T - 1) blockSums[blockIdx.x] = s[t];
}

__global__ __launch_bounds__(SCAN_T) void k_scan_sums(int* __restrict__ blockSums, int nb) {
    __shared__ int s[SCAN_T];
    int t = threadIdx.x;
    int v = (t < nb) ? blockSums[t] : 0;
    s[t] = v;
    __syncthreads();
    for (int d = 1; d < SCAN_T; d <<= 1) {
        int y = (t >= d) ? s[t - d] : 0;
        __syncthreads();
        s[t] += y;
        __syncthreads();
    }
    if (t < nb) blockSums[t] = s[t] - v;   // exclusive
}

__global__ __launch_bounds__(SCAN_T) void k_finalize(int* __restrict__ rowStart,
                                                     const int* __restrict__ blockSums,
                                                     int n, int E, int* __restrict__ cursor) {
    int t = threadIdx.x;
    int i = blockIdx.x * SCAN_T + t;
    if (i < n) {
        int v = rowStart[i] + blockSums[blockIdx.x];
        rowStart[i] = v;
        cursor[i]   = v;
    }
    if (i == 0) rowStart[n] = E;
}

// ---------- bucket sources by target
__global__ void k_fill(const int* __restrict__ ei, int E, int* __restrict__ cursor,
                       int* __restrict__ sortedRow) {
    int e = blockIdx.x * blockDim.x + threadIdx.x;
    if (e < E) {
        int r = ei[e];          // source
        int c = ei[E + e];      // target
        int p = atomicAdd(&cursor[c], 1);
        sortedRow[p] = r;
    }
}

// ---------- g = fp16( dinv * (x @ WcT) ); 16 rows x 128 outs per block, f32 VALU
__global__ __launch_bounds__(128) void k_gemm(const float* __restrict__ x,
                                              const float* __restrict__ WcT,
                                              const int* __restrict__ cnt,
                                              __half* __restrict__ g, int n) {
    __shared__ float xs[GR * KDIM];
    int o = threadIdx.x;                       // output dim 0..127
    long n0 = (long)blockIdx.x * GR;
    const float4* xv = (const float4*)(x + n0 * KDIM);
    float4* sv = (float4*)xs;
#pragma unroll
    for (int idx = o; idx < GR * KDIM / 4; idx += 128) sv[idx] = xv[idx];
    __syncthreads();

    float acc[GR];
#pragma unroll
    for (int r = 0; r < GR; ++r) acc[r] = 0.f;

    for (int k4 = 0; k4 < KDIM / 4; ++k4) {
        float w0 = WcT[(k4 * 4 + 0) * NDIM + o];
        float w1 = WcT[(k4 * 4 + 1) * NDIM + o];
        float w2 = WcT[(k4 * 4 + 2) * NDIM + o];
        float w3 = WcT[(k4 * 4 + 3) * NDIM + o];
#pragma unroll
        for (int r = 0; r < GR; ++r) {
            float4 xr = *(const float4*)&xs[r * KDIM + k4 * 4];
            acc[r] = fmaf(xr.x, w0, acc[r]);
            acc[r] = fmaf(xr.y, w1, acc[r]);
            acc[r] = fmaf(xr.z, w2, acc[r]);
            acc[r] = fmaf(xr.w, w3, acc[r]);
        }
    }
#pragma unroll
    for (int r = 0; r < GR; ++r) {
        long node = n0 + r;
        float di = rsqrtf((float)(cnt[node] + 1));   // deg = cnt + self-loop
        g[node * NDIM + o] = __float2half_rn(acc[r] * di);
    }
}

// ---------- gather + scale + bias + row L2-normalize (one WAVE per node, half2 msgs)
__global__ __launch_bounds__(256) void k_gather(const __half2* __restrict__ g,
                                                const int* __restrict__ rowStart,
                                                const int* __restrict__ sortedRow,
                                                const int* __restrict__ cnt,
                                                const float* __restrict__ bg,
                                                float* __restrict__ out) {
    int lane = threadIdx.x & 63;
    int i = blockIdx.x * 4 + (threadIdx.x >> 6);   // node, N divisible by 4
    const int s = rowStart[i];
    const int e = rowStart[i + 1];
    const size_t stride = NDIM / 2;                 // 64 half2 per row

    __half2 self = g[(size_t)i * stride + lane];
    float ax = __low2float(self), ay = __high2float(self);

    int p = s;
    for (; p + 4 <= e; p += 4) {
        int r0 = sortedRow[p + 0];
        int r1 = sortedRow[p + 1];
        int r2 = sortedRow[p + 2];
        int r3 = sortedRow[p + 3];
        __half2 m0 = g[(size_t)r0 * stride + lane];
        __half2 m1 = g[(size_t)r1 * stride + lane];
        __half2 m2 = g[(size_t)r2 * stride + lane];
        __half2 m3 = g[(size_t)r3 * stride + lane];
        ax += __low2float(m0) + __low2float(m1) + __low2float(m2) + __low2float(m3);
        ay += __high2float(m0) + __high2float(m1) + __high2float(m2) + __high2float(m3);
    }
    for (; p < e; ++p) {
        int r = sortedRow[p];
        __half2 m = g[(size_t)r * stride + lane];
        ax += __low2float(m);
        ay += __high2float(m);
    }

    float di = rsqrtf((float)(cnt[i] + 1));
    float2 b = ((const float2*)bg)[lane];
    float v0 = fmaf(di, ax, b.x);
    float v1 = fmaf(di, ay, b.y);

    float sq = v0 * v0 + v1 * v1;
#pragma unroll
    for (int d = 32; d > 0; d >>= 1) sq += __shfl_xor(sq, d);
    float scale = 1.0f / fmaxf(sqrtf(sq), 1e-12f);
    ((float2*)out)[(size_t)i * stride + lane] = make_float2(v0 * scale, v1 * scale);
}

extern "C" void kernel_launch(void* const* d_in, const int* in_sizes, int n_in,
                              void* d_out, int out_size, void* d_ws, size_t ws_size,
                              hipStream_t stream) {
    const float* x  = (const float*)d_in[0];
    const int*   ei = (const int*)  d_in[1];
    const float* Wp = (const float*)d_in[2];
    const float* Wg = (const float*)d_in[3];
    const float* bg = (const float*)d_in[4];
    float* out = (float*)d_out;

    const int N = in_sizes[0] / KDIM;   // 100000
    const int E = in_sizes[1] / 2;      // 1600000

    // carve workspace (256B aligned)
    char* p = (char*)d_ws;
    auto carve = [&](size_t bytes) { void* r = (void*)p; p += (bytes + 255) & ~(size_t)255; return r; };
    __half* g        = (__half*)carve((size_t)N * NDIM * 2);  // 25.6 MB
    int*   sortedRow = (int*)  carve((size_t)E * 4);          // 6.4 MB
    float* WcT       = (float*)carve((size_t)KDIM * NDIM * 4);
    int*   cnt       = (int*)  carve((size_t)N * 4);
    int*   rowStart  = (int*)  carve((size_t)(N + 1) * 4);
    int*   cursor    = (int*)  carve((size_t)N * 4);
    int*   blockSums = (int*)  carve((size_t)SCAN_T * 4);

    int nb = (N + SCAN_T - 1) / SCAN_T;   // 98 (fits in one SCAN_T-wide scan)

    hipLaunchKernelGGL(k_combine_w, dim3(NDIM), dim3(KDIM), 0, stream, Wp, Wg, WcT);
    hipLaunchKernelGGL(k_zero, dim3((N + 255) / 256), dim3(256), 0, stream, cnt, N);
    hipLaunchKernelGGL(k_hist, dim3((E + 255) / 256), dim3(256), 0, stream, ei + E, cnt, E);
    hipLaunchKernelGGL(k_scan_blocks, dim3(nb), dim3(SCAN_T), 0, stream, cnt, N, rowStart, blockSums);
    hipLaunchKernelGGL(k_scan_sums, dim3(1), dim3(SCAN_T), 0, stream, blockSums, nb);
    hipLaunchKernelGGL(k_finalize, dim3(nb), dim3(SCAN_T), 0, stream, rowStart, blockSums, N, E, cursor);
    hipLaunchKernelGGL(k_fill, dim3((E + 255) / 256), dim3(256), 0, stream, ei, E, cursor, sortedRow);
    hipLaunchKernelGGL(k_gemm, dim3(N / GR), dim3(NDIM), 0, stream, x, WcT, cnt, g, N);
    hipLaunchKernelGGL(k_gather, dim3(N / 4), dim3(256), 0, stream,
                       (const __half2*)g, rowStart, sortedRow, cnt, bg, out);
}

// Round 4
// 456.527 us; speedup vs baseline: 1.4478x; 1.2467x over previous
//
#include <hip/hip_runtime.h>
#include <hip/hip_fp16.h>

#define NDIM 128     // OUT_DIM
#define KDIM 256     // IN_DIM
#define SCAN_T 1024
#define MT 5         // M-tiles (of 16 rows) per GEMM block
#define AROW 264     // LDS A-row stride in halfs (264*2=528 bytes, 16B-aligned, breaks pow2)

typedef _Float16 half8 __attribute__((ext_vector_type(8)));
typedef float float4v __attribute__((ext_vector_type(4)));

// ---------- Wc = Wg @ Wp, written directly in MFMA B-fragment layout (fp16)
// Bfrag[((ntile*8 + kk)*64 + lane)*8 + j] = Wc[n][k],
//   n = ntile*16 + (lane&15), k = kk*32 + (lane>>4)*8 + j
__global__ void k_combine_w(const float* __restrict__ Wp, const float* __restrict__ Wg,
                            _Float16* __restrict__ Bfrag) {
    int o = blockIdx.x;      // n: 0..127
    int i = threadIdx.x;     // k: 0..255
    float acc = 0.f;
#pragma unroll 4
    for (int k = 0; k < 128; ++k) acc = fmaf(Wg[o * 128 + k], Wp[k * 256 + i], acc);
    int kk = i >> 5, r = i & 31, quad = r >> 3, j = r & 7;
    int ntile = o >> 4, lanen = o & 15, lane = quad * 16 + lanen;
    Bfrag[(((ntile * 8 + kk) * 64) + lane) * 8 + j] = (_Float16)acc;
}

__global__ void k_zero(int* __restrict__ p, int n) {
    int i = blockIdx.x * blockDim.x + threadIdx.x;
    if (i < n) p[i] = 0;
}

// ---------- histogram of target (col) indices
__global__ void k_hist(const int* __restrict__ col, int* __restrict__ cnt, int E) {
    int e = blockIdx.x * blockDim.x + threadIdx.x;
    if (e < E) atomicAdd(&cnt[col[e]], 1);
}

// ---------- exclusive scan, 3-kernel version (N=100000 -> 98 tiles of 1024)
__global__ __launch_bounds__(SCAN_T) void k_scan_blocks(const int* __restrict__ cnt, int n,
                                                        int* __restrict__ excl,
                                                        int* __restrict__ blockSums) {
    __shared__ int s[SCAN_T];
    int t = threadIdx.x;
    int i = blockIdx.x * SCAN_T + t;
    int v = (i < n) ? cnt[i] : 0;
    s[t] = v;
    __syncthreads();
    for (int d = 1; d < SCAN_T; d <<= 1) {
        int y = (t >= d) ? s[t - d] : 0;
        __syncthreads();
        s[t] += y;
        __syncthreads();
    }
    if (i < n) excl[i] = s[t] - v;
    if (t == SCAN_T - 1) blockSums[blockIdx.x] = s[t];
}

__global__ __launch_bounds__(SCAN_T) void k_scan_sums(int* __restrict__ blockSums, int nb) {
    __shared__ int s[SCAN_T];
    int t = threadIdx.x;
    int v = (t < nb) ? blockSums[t] : 0;
    s[t] = v;
    __syncthreads();
    for (int d = 1; d < SCAN_T; d <<= 1) {
        int y = (t >= d) ? s[t - d] : 0;
        __syncthreads();
        s[t] += y;
        __syncthreads();
    }
    if (t < nb) blockSums[t] = s[t] - v;   // exclusive
}

__global__ __launch_bounds__(SCAN_T) void k_finalize(int* __restrict__ rowStart,
                                                     const int* __restrict__ blockSums,
                                                     int n, int E, int* __restrict__ cursor) {
    int t = threadIdx.x;
    int i = blockIdx.x * SCAN_T + t;
    if (i < n) {
        int v = rowStart[i] + blockSums[blockIdx.x];
        rowStart[i] = v;
        cursor[i]   = v;
    }
    if (i == 0) rowStart[n] = E;
}

// ---------- bucket sources by target
__global__ void k_fill(const int* __restrict__ ei, int E, int* __restrict__ cursor,
                       int* __restrict__ sortedRow) {
    int e = blockIdx.x * blockDim.x + threadIdx.x;
    if (e < E) {
        int r = ei[e];          // source
        int c = ei[E + e];      // target
        int p = atomicAdd(&cursor[c], 1);
        sortedRow[p] = r;
    }
}

// ---------- g = fp16( dinv * (x @ Wc^T) ) via MFMA 16x16x32 f16
// 256 threads = 4 waves; wave w covers n-tiles {w, w+4}; MT M-tiles of 16 rows.
__global__ __launch_bounds__(256) void k_gemm_mfma(const float* __restrict__ x,
                                                   const _Float16* __restrict__ Bfrag,
                                                   const int* __restrict__ cnt,
                                                   _Float16* __restrict__ g, int nrows) {
    __shared__ __align__(16) _Float16 xs[16 * AROW];
    int tid  = threadIdx.x;
    int lane = tid & 63;
    int w    = tid >> 6;      // wave 0..3
    int quad = lane >> 4;
    int lcol = lane & 15;

    // B fragments for this wave's two n-tiles (coalesced 16B/lane, once per block)
    const half8* Bv = (const half8*)Bfrag;
    half8 b0[8], b1[8];
#pragma unroll
    for (int kk = 0; kk < 8; ++kk) {
        b0[kk] = Bv[(w * 8 + kk) * 64 + lane];
        b1[kk] = Bv[((w + 4) * 8 + kk) * 64 + lane];
    }

    long base = (long)blockIdx.x * (16 * MT);
    for (int t = 0; t < MT; ++t) {
        long m0 = base + t * 16;
        __syncthreads();                     // protect xs reuse
        const float4* xv = (const float4*)(x + m0 * KDIM);
#pragma unroll
        for (int ii = 0; ii < 4; ++ii) {
            int idx = tid + ii * 256;        // 0..1023 over 16 rows x 64 float4
            int m = idx >> 6, k4 = idx & 63;
            float4 v = xv[idx];
            _Float16* d = &xs[m * AROW + k4 * 4];
            d[0] = (_Float16)v.x; d[1] = (_Float16)v.y;
            d[2] = (_Float16)v.z; d[3] = (_Float16)v.w;
        }
        __syncthreads();

        float4v acc0 = {0.f, 0.f, 0.f, 0.f}, acc1 = {0.f, 0.f, 0.f, 0.f};
#pragma unroll
        for (int kk = 0; kk < 8; ++kk) {
            half8 a = *(const half8*)(&xs[lcol * AROW + kk * 32 + quad * 8]);
            acc0 = __builtin_amdgcn_mfma_f32_16x16x32_f16(a, b0[kk], acc0, 0, 0, 0);
            acc1 = __builtin_amdgcn_mfma_f32_16x16x32_f16(a, b1[kk], acc1, 0, 0, 0);
        }

        // C/D layout: col = lane&15, row = quad*4 + reg
#pragma unroll
        for (int r = 0; r < 4; ++r) {
            long node = m0 + quad * 4 + r;
            float di = rsqrtf((float)(cnt[node] + 1));   // deg = cnt + self-loop
            g[node * NDIM + w * 16 + lcol]        = (_Float16)(acc0[r] * di);
            g[node * NDIM + (w + 4) * 16 + lcol]  = (_Float16)(acc1[r] * di);
        }
    }
}

// ---------- gather + scale + bias + row L2-normalize (one WAVE per node, half2 msgs)
__global__ __launch_bounds__(256) void k_gather(const __half2* __restrict__ g,
                                                const int* __restrict__ rowStart,
                                                const int* __restrict__ sortedRow,
                                                const int* __restrict__ cnt,
                                                const float* __restrict__ bg,
                                                float* __restrict__ out) {
    int lane = threadIdx.x & 63;
    int i = blockIdx.x * 4 + (threadIdx.x >> 6);   // node, N divisible by 4
    const int s = rowStart[i];
    const int e = rowStart[i + 1];
    const size_t stride = NDIM / 2;                 // 64 half2 per row

    __half2 self = g[(size_t)i * stride + lane];
    float ax = __low2float(self), ay = __high2float(self);

    int p = s;
    for (; p + 4 <= e; p += 4) {
        int r0 = sortedRow[p + 0];
        int r1 = sortedRow[p + 1];
        int r2 = sortedRow[p + 2];
        int r3 = sortedRow[p + 3];
        __half2 m0 = g[(size_t)r0 * stride + lane];
        __half2 m1 = g[(size_t)r1 * stride + lane];
        __half2 m2 = g[(size_t)r2 * stride + lane];
        __half2 m3 = g[(size_t)r3 * stride + lane];
        ax += __low2float(m0) + __low2float(m1) + __low2float(m2) + __low2float(m3);
        ay += __high2float(m0) + __high2float(m1) + __high2float(m2) + __high2float(m3);
    }
    for (; p < e; ++p) {
        int r = sortedRow[p];
        __half2 m = g[(size_t)r * stride + lane];
        ax += __low2float(m);
        ay += __high2float(m);
    }

    float di = rsqrtf((float)(cnt[i] + 1));
    float2 b = ((const float2*)bg)[lane];
    float v0 = fmaf(di, ax, b.x);
    float v1 = fmaf(di, ay, b.y);

    float sq = v0 * v0 + v1 * v1;
#pragma unroll
    for (int d = 32; d > 0; d >>= 1) sq += __shfl_xor(sq, d);
    float scale = 1.0f / fmaxf(sqrtf(sq), 1e-12f);
    ((float2*)out)[(size_t)i * stride + lane] = make_float2(v0 * scale, v1 * scale);
}

extern "C" void kernel_launch(void* const* d_in, const int* in_sizes, int n_in,
                              void* d_out, int out_size, void* d_ws, size_t ws_size,
                              hipStream_t stream) {
    const float* x  = (const float*)d_in[0];
    const int*   ei = (const int*)  d_in[1];
    const float* Wp = (const float*)d_in[2];
    const float* Wg = (const float*)d_in[3];
    const float* bg = (const float*)d_in[4];
    float* out = (float*)d_out;

    const int N = in_sizes[0] / KDIM;   // 100000
    const int E = in_sizes[1] / 2;      // 1600000

    // carve workspace (256B aligned)
    char* p = (char*)d_ws;
    auto carve = [&](size_t bytes) { void* r = (void*)p; p += (bytes + 255) & ~(size_t)255; return r; };
    _Float16* g      = (_Float16*)carve((size_t)N * NDIM * 2);  // 25.6 MB
    int*   sortedRow = (int*)  carve((size_t)E * 4);            // 6.4 MB
    _Float16* Bfrag  = (_Float16*)carve((size_t)KDIM * NDIM * 2);
    int*   cnt       = (int*)  carve((size_t)N * 4);
    int*   rowStart  = (int*)  carve((size_t)(N + 1) * 4);
    int*   cursor    = (int*)  carve((size_t)N * 4);
    int*   blockSums = (int*)  carve((size_t)SCAN_T * 4);

    int nb = (N + SCAN_T - 1) / SCAN_T;   // 98 (fits in one SCAN_T-wide scan)

    hipLaunchKernelGGL(k_combine_w, dim3(NDIM), dim3(KDIM), 0, stream, Wp, Wg, Bfrag);
    hipLaunchKernelGGL(k_zero, dim3((N + 255) / 256), dim3(256), 0, stream, cnt, N);
    hipLaunchKernelGGL(k_hist, dim3((E + 255) / 256), dim3(256), 0, stream, ei + E, cnt, E);
    hipLaunchKernelGGL(k_scan_blocks, dim3(nb), dim3(SCAN_T), 0, stream, cnt, N, rowStart, blockSums);
    hipLaunchKernelGGL(k_scan_sums, dim3(1), dim3(SCAN_T), 0, stream, blockSums, nb);
    hipLaunchKernelGGL(k_finalize, dim3(nb), dim3(SCAN_T), 0, stream, rowStart, blockSums, N, E, cursor);
    hipLaunchKernelGGL(k_fill, dim3((E + 255) / 256), dim3(256), 0, stream, ei, E, cursor, sortedRow);
    hipLaunchKernelGGL(k_gemm_mfma, dim3(N / (16 * MT)), dim3(256), 0, stream, x, Bfrag, cnt, g, N);
    hipLaunchKernelGGL(k_gather, dim3(N / 4), dim3(256), 0, stream,
                       (const __half2*)g, rowStart, sortedRow, cnt, bg, out);
}

// Round 5
// 364.260 us; speedup vs baseline: 1.8146x; 1.2533x over previous
//
#include <hip/hip_runtime.h>
#include <hip/hip_fp16.h>

#define NDIM 128     // OUT_DIM
#define KDIM 256     // IN_DIM
#define MT 5         // M-tiles (of 16 rows) per GEMM block
#define AROW 264     // LDS A-row stride in halfs (16B-aligned, breaks pow2)
#define CHUNK 6400   // edges per phase1/phase3 block
#define MAXBUCK 128  // LDS histogram capacity (buckets = N/1024 <= 128)

typedef _Float16 half8 __attribute__((ext_vector_type(8)));
typedef float float4v __attribute__((ext_vector_type(4)));

// ---------- Wc = Wg @ Wp, written directly in MFMA B-fragment layout (fp16)
// Bfrag[((ntile*8 + kk)*64 + lane)*8 + j] = Wc[n][k],
//   n = ntile*16 + (lane&15), k = kk*32 + (lane>>4)*8 + j
__global__ void k_combine_w(const float* __restrict__ Wp, const float* __restrict__ Wg,
                            _Float16* __restrict__ Bfrag) {
    int o = blockIdx.x;      // n: 0..127
    int i = threadIdx.x;     // k: 0..255
    float acc = 0.f;
#pragma unroll 4
    for (int k = 0; k < 128; ++k) acc = fmaf(Wg[o * 128 + k], Wp[k * 256 + i], acc);
    int kk = i >> 5, r = i & 31, quad = r >> 3, j = r & 7;
    int ntile = o >> 4, lanen = o & 15, lane = quad * 16 + lanen;
    Bfrag[(((ntile * 8 + kk) * 64) + lane) * 8 + j] = (_Float16)acc;
}

// ---------- CSR build, pass 1: per-block coarse histogram (bucket = tgt>>10)
__global__ __launch_bounds__(256) void k_phase1(const int* __restrict__ col, int E,
                                                int* __restrict__ hist, int NBLK, int NBUCK) {
    __shared__ int h[MAXBUCK];
    int tid = threadIdx.x;
    if (tid < MAXBUCK) h[tid] = 0;
    __syncthreads();
    int e0 = blockIdx.x * CHUNK;
    int e1 = min(e0 + CHUNK, E);
    for (int e = e0 + tid; e < e1; e += 256) atomicAdd(&h[col[e] >> 10], 1);
    __syncthreads();
    if (tid < NBUCK) hist[tid * NBLK + blockIdx.x] = h[tid];
}

// ---------- CSR build, pass 2: in-place exclusive scan of hist (bucket-major)
__global__ __launch_bounds__(1024) void k_scan2(int* __restrict__ hist, int NE) {
    __shared__ int s[1024];
    int t = threadIdx.x;
    int CH = (NE + 1023) >> 10;
    int off = t * CH;
    int sum = 0;
    for (int j = 0; j < CH; ++j) { int idx = off + j; if (idx < NE) sum += hist[idx]; }
    s[t] = sum;
    __syncthreads();
    for (int d = 1; d < 1024; d <<= 1) {
        int y = (t >= d) ? s[t - d] : 0;
        __syncthreads();
        s[t] += y;
        __syncthreads();
    }
    int run = s[t] - sum;   // exclusive prefix of this thread's range
    for (int j = 0; j < CH; ++j) {
        int idx = off + j;
        if (idx < NE) { int v = hist[idx]; hist[idx] = run; run += v; }
    }
}

// ---------- CSR build, pass 3: scatter (src,tgt) pairs into per-(bucket,block) runs
__global__ __launch_bounds__(256) void k_phase3(const int* __restrict__ ei, int E,
                                                const int* __restrict__ offs, int NBLK, int NBUCK,
                                                int2* __restrict__ tmp) {
    __shared__ int cur[MAXBUCK];
    int tid = threadIdx.x;
    if (tid < NBUCK) cur[tid] = offs[tid * NBLK + blockIdx.x];
    __syncthreads();
    int e0 = blockIdx.x * CHUNK;
    int e1 = min(e0 + CHUNK, E);
    for (int e = e0 + tid; e < e1; e += 256) {
        int r = ei[e];          // source
        int c = ei[E + e];      // target
        int p = atomicAdd(&cur[c >> 10], 1);
        tmp[p] = make_int2(r, c);
    }
}

// ---------- CSR build, pass 4: per-bucket fine counting sort (1024 nodes/bucket)
__global__ __launch_bounds__(1024) void k_fine(const int2* __restrict__ tmp,
                                               const int* __restrict__ offs, int NBLK, int NBUCK,
                                               int N, int E,
                                               int* __restrict__ sortedRow,
                                               int* __restrict__ cnt,
                                               int* __restrict__ rowStart) {
    __shared__ int scnt[1024];
    __shared__ int cur[1024];
    int b = blockIdx.x;
    int t = threadIdx.x;
    int nodeBase = b << 10;
    int start = offs[b * NBLK];
    int end = (b + 1 < NBUCK) ? offs[(b + 1) * NBLK] : E;

    scnt[t] = 0;
    __syncthreads();
    for (int p = start + t; p < end; p += 1024) atomicAdd(&scnt[tmp[p].y - nodeBase], 1);
    __syncthreads();
    int v = scnt[t];
    // inclusive scan
    for (int d = 1; d < 1024; d <<= 1) {
        int y = (t >= d) ? scnt[t - d] : 0;
        __syncthreads();
        scnt[t] += y;
        __syncthreads();
    }
    int excl = scnt[t] - v;
    int node = nodeBase + t;
    if (node < N) {
        cnt[node] = v;
        rowStart[node] = start + excl;
    }
    cur[t] = start + excl;
    __syncthreads();
    for (int p = start + t; p < end; p += 1024) {
        int2 pr = tmp[p];
        int slot = atomicAdd(&cur[pr.y - nodeBase], 1);
        sortedRow[slot] = pr.x;
    }
    if (b == NBUCK - 1 && t == 0) rowStart[N] = E;
}

// ---------- g = fp16( dinv * (x @ Wc^T) ) via MFMA 16x16x32 f16
__global__ __launch_bounds__(256) void k_gemm_mfma(const float* __restrict__ x,
                                                   const _Float16* __restrict__ Bfrag,
                                                   const int* __restrict__ cnt,
                                                   _Float16* __restrict__ g, int nrows) {
    __shared__ __align__(16) _Float16 xs[16 * AROW];
    int tid  = threadIdx.x;
    int lane = tid & 63;
    int w    = tid >> 6;      // wave 0..3
    int quad = lane >> 4;
    int lcol = lane & 15;

    const half8* Bv = (const half8*)Bfrag;
    half8 b0[8], b1[8];
#pragma unroll
    for (int kk = 0; kk < 8; ++kk) {
        b0[kk] = Bv[(w * 8 + kk) * 64 + lane];
        b1[kk] = Bv[((w + 4) * 8 + kk) * 64 + lane];
    }

    long base = (long)blockIdx.x * (16 * MT);
    for (int t = 0; t < MT; ++t) {
        long m0 = base + t * 16;
        __syncthreads();                     // protect xs reuse
        const float4* xv = (const float4*)(x + m0 * KDIM);
#pragma unroll
        for (int ii = 0; ii < 4; ++ii) {
            int idx = tid + ii * 256;        // 0..1023 over 16 rows x 64 float4
            int m = idx >> 6, k4 = idx & 63;
            float4 v = xv[idx];
            _Float16* d = &xs[m * AROW + k4 * 4];
            d[0] = (_Float16)v.x; d[1] = (_Float16)v.y;
            d[2] = (_Float16)v.z; d[3] = (_Float16)v.w;
        }
        __syncthreads();

        float4v acc0 = {0.f, 0.f, 0.f, 0.f}, acc1 = {0.f, 0.f, 0.f, 0.f};
#pragma unroll
        for (int kk = 0; kk < 8; ++kk) {
            half8 a = *(const half8*)(&xs[lcol * AROW + kk * 32 + quad * 8]);
            acc0 = __builtin_amdgcn_mfma_f32_16x16x32_f16(a, b0[kk], acc0, 0, 0, 0);
            acc1 = __builtin_amdgcn_mfma_f32_16x16x32_f16(a, b1[kk], acc1, 0, 0, 0);
        }

        // C/D layout: col = lane&15, row = quad*4 + reg
#pragma unroll
        for (int r = 0; r < 4; ++r) {
            long node = m0 + quad * 4 + r;
            float di = rsqrtf((float)(cnt[node] + 1));   // deg = cnt + self-loop
            g[node * NDIM + w * 16 + lcol]        = (_Float16)(acc0[r] * di);
            g[node * NDIM + (w + 4) * 16 + lcol]  = (_Float16)(acc1[r] * di);
        }
    }
}

// ---------- gather + scale + bias + row L2-normalize (one WAVE per node, half2 msgs)
__global__ __launch_bounds__(256) void k_gather(const __half2* __restrict__ g,
                                                const int* __restrict__ rowStart,
                                                const int* __restrict__ sortedRow,
                                                const int* __restrict__ cnt,
                                                const float* __restrict__ bg,
                                                float* __restrict__ out) {
    int lane = threadIdx.x & 63;
    int i = blockIdx.x * 4 + (threadIdx.x >> 6);   // node, N divisible by 4
    const int s = rowStart[i];
    const int e = rowStart[i + 1];
    const size_t stride = NDIM / 2;                 // 64 half2 per row

    __half2 self = g[(size_t)i * stride + lane];
    float ax = __low2float(self), ay = __high2float(self);

    int p = s;
    for (; p + 4 <= e; p += 4) {
        int r0 = sortedRow[p + 0];
        int r1 = sortedRow[p + 1];
        int r2 = sortedRow[p + 2];
        int r3 = sortedRow[p + 3];
        __half2 m0 = g[(size_t)r0 * stride + lane];
        __half2 m1 = g[(size_t)r1 * stride + lane];
        __half2 m2 = g[(size_t)r2 * stride + lane];
        __half2 m3 = g[(size_t)r3 * stride + lane];
        ax += __low2float(m0) + __low2float(m1) + __low2float(m2) + __low2float(m3);
        ay += __high2float(m0) + __high2float(m1) + __high2float(m2) + __high2float(m3);
    }
    for (; p < e; ++p) {
        int r = sortedRow[p];
        __half2 m = g[(size_t)r * stride + lane];
        ax += __low2float(m);
        ay += __high2float(m);
    }

    float di = rsqrtf((float)(cnt[i] + 1));
    float2 b = ((const float2*)bg)[lane];
    float v0 = fmaf(di, ax, b.x);
    float v1 = fmaf(di, ay, b.y);

    float sq = v0 * v0 + v1 * v1;
#pragma unroll
    for (int d = 32; d > 0; d >>= 1) sq += __shfl_xor(sq, d);
    float scale = 1.0f / fmaxf(sqrtf(sq), 1e-12f);
    ((float2*)out)[(size_t)i * stride + lane] = make_float2(v0 * scale, v1 * scale);
}

extern "C" void kernel_launch(void* const* d_in, const int* in_sizes, int n_in,
                              void* d_out, int out_size, void* d_ws, size_t ws_size,
                              hipStream_t stream) {
    const float* x  = (const float*)d_in[0];
    const int*   ei = (const int*)  d_in[1];
    const float* Wp = (const float*)d_in[2];
    const float* Wg = (const float*)d_in[3];
    const float* bg = (const float*)d_in[4];
    float* out = (float*)d_out;

    const int N = in_sizes[0] / KDIM;   // 100000
    const int E = in_sizes[1] / 2;      // 1600000

    const int NBLK  = (E + CHUNK - 1) / CHUNK;   // 250
    const int NBUCK = (N + 1023) >> 10;          // 98
    const int NE    = NBLK * NBUCK;              // 24500

    // carve workspace (256B aligned)
    char* p = (char*)d_ws;
    auto carve = [&](size_t bytes) { void* r = (void*)p; p += (bytes + 255) & ~(size_t)255; return r; };
    _Float16* g      = (_Float16*)carve((size_t)N * NDIM * 2);  // 25.6 MB
    int*   sortedRow = (int*)  carve((size_t)E * 4);            // 6.4 MB
    int2*  tmp       = (int2*) carve((size_t)E * 8);            // 12.8 MB
    _Float16* Bfrag  = (_Float16*)carve((size_t)KDIM * NDIM * 2);
    int*   cnt       = (int*)  carve((size_t)N * 4);
    int*   rowStart  = (int*)  carve((size_t)(N + 1) * 4);
    int*   hist      = (int*)  carve((size_t)NE * 4);

    hipLaunchKernelGGL(k_combine_w, dim3(NDIM), dim3(KDIM), 0, stream, Wp, Wg, Bfrag);
    hipLaunchKernelGGL(k_phase1, dim3(NBLK), dim3(256), 0, stream, ei + E, E, hist, NBLK, NBUCK);
    hipLaunchKernelGGL(k_scan2, dim3(1), dim3(1024), 0, stream, hist, NE);
    hipLaunchKernelGGL(k_phase3, dim3(NBLK), dim3(256), 0, stream, ei, E, hist, NBLK, NBUCK, tmp);
    hipLaunchKernelGGL(k_fine, dim3(NBUCK), dim3(1024), 0, stream, tmp, hist, NBLK, NBUCK, N, E,
                       sortedRow, cnt, rowStart);
    hipLaunchKernelGGL(k_gemm_mfma, dim3(N / (16 * MT)), dim3(256), 0, stream, x, Bfrag, cnt, g, N);
    hipLaunchKernelGGL(k_gather, dim3(N / 4), dim3(256), 0, stream,
                       (const __half2*)g, rowStart, sortedRow, cnt, bg, out);
}